// Round 1
// baseline (173.818 us; speedup 1.0000x reference)
//
#include <hip/hip_runtime.h>

#define NW    20
#define BATCH 32
#define DIM   (1u << 20)

// skewed LDS index: breaks power-of-2 stride bank conflicts, injective for i<4096
#define SK(i) ((i) + ((i) >> 5))

struct Coef { float a, d, e, f; };

// n0 = (a+id)x0 + (-e-if)x1 ; n1 = (e-if)x0 + (a-id)x1
__device__ __forceinline__ void bfly(float& x0r, float& x0i, float& x1r, float& x1i,
                                     float a, float d, float e, float f) {
    float n0r = fmaf(a, x0r, fmaf(-d, x0i, fmaf(-e, x1r,  f * x1i)));
    float n0i = fmaf(a, x0i, fmaf( d, x0r, fmaf(-e, x1i, -f * x1r)));
    float n1r = fmaf(e, x0r, fmaf( f, x0i, fmaf( a, x1r,  d * x1i)));
    float n1i = fmaf(e, x0i, fmaf(-f, x0r, fmaf( a, x1i, -d * x1r)));
    x0r = n0r; x0i = n0i; x1r = n1r; x1i = n1i;
}

template<int JB>
__device__ __forceinline__ void stage16(float (&re)[16], float (&im)[16], Coef u) {
    #pragma unroll
    for (int base = 0; base < 16; ++base)
        if (!(base & (1 << JB)))
            bfly(re[base], im[base], re[base | (1 << JB)], im[base | (1 << JB)],
                 u.a, u.d, u.e, u.f);
}

// ---------------------------------------------------------------------------
// Pass 1: wires 8..19 (y bits 0..11). Block = 4096 consecutive amplitudes.
// 3 register rounds (4 bits each) with skewed-LDS ownership exchanges.
// ---------------------------------------------------------------------------
__global__ __launch_bounds__(256) void pass1(const float* __restrict__ state,
                                             const float* __restrict__ params,
                                             float2* __restrict__ amp) {
    __shared__ float lre[4224];
    __shared__ float lim[4224];
    __shared__ Coef  coef[12];          // coef[k] = wire k+8
    const int t     = threadIdx.x;
    const int b     = blockIdx.x >> 8;
    const int chunk = blockIdx.x & 255;

    if (t < 12) {
        int w = t + 8;
        double s1, c1, s2, c2;
        sincos(0.5 * (double)params[w],      &s1, &c1);   // RX
        sincos(0.5 * (double)params[w + NW], &s2, &c2);   // RY
        coef[t].a = (float)(c1 * c2);
        coef[t].d = (float)(s1 * s2);
        coef[t].e = (float)(s2 * c1);
        coef[t].f = (float)(c2 * s1);
    }

    const float* src = state + ((size_t)b << 20) + ((size_t)chunk << 12);
    #pragma unroll
    for (int k = 0; k < 16; ++k) {      // coalesced stage-in (real input)
        int i = k * 256 + t;
        lre[SK(i)] = src[i];
    }
    __syncthreads();

    float re[16], im[16];
    // Round 1: own idx bits 0..3  (idx = t*16 + r)
    #pragma unroll
    for (int r = 0; r < 16; ++r) { re[r] = lre[SK(t * 16 + r)]; im[r] = 0.f; }
    stage16<0>(re, im, coef[11]);  // bit 0 -> wire 19
    stage16<1>(re, im, coef[10]);
    stage16<2>(re, im, coef[9]);
    stage16<3>(re, im, coef[8]);
    // exchange 1 (write-set == own read-set; barrier only before re-read)
    #pragma unroll
    for (int r = 0; r < 16; ++r) { int i = t * 16 + r; lre[SK(i)] = re[r]; lim[SK(i)] = im[r]; }
    __syncthreads();

    // Round 2: own idx bits 4..7  (idx = (t>>4)*256 + r*16 + (t&15))
    const int base2 = (t >> 4) * 256 + (t & 15);
    #pragma unroll
    for (int r = 0; r < 16; ++r) { int i = base2 + r * 16; re[r] = lre[SK(i)]; im[r] = lim[SK(i)]; }
    stage16<0>(re, im, coef[7]);   // bit 4 -> wire 15
    stage16<1>(re, im, coef[6]);
    stage16<2>(re, im, coef[5]);
    stage16<3>(re, im, coef[4]);
    #pragma unroll
    for (int r = 0; r < 16; ++r) { int i = base2 + r * 16; lre[SK(i)] = re[r]; lim[SK(i)] = im[r]; }
    __syncthreads();

    // Round 3: own idx bits 8..11 (idx = r*256 + t)
    #pragma unroll
    for (int r = 0; r < 16; ++r) { int i = r * 256 + t; re[r] = lre[SK(i)]; im[r] = lim[SK(i)]; }
    stage16<0>(re, im, coef[3]);   // bit 8 -> wire 11
    stage16<1>(re, im, coef[2]);
    stage16<2>(re, im, coef[1]);
    stage16<3>(re, im, coef[0]);

    float2* dst = amp + ((size_t)b << 20) + ((size_t)chunk << 12);
    #pragma unroll
    for (int r = 0; r < 16; ++r)        // coalesced: 64 consecutive float2/wave
        dst[r * 256 + t] = make_float2(re[r], im[r]);
}

// ---------------------------------------------------------------------------
// Pass 2: wires 0..7 (y bits 12..19) + fused |psi|^2 * g(y) reduction.
// Block tile: all 256 high values x 16 consecutive low offsets.
// g(y) = A(h) + sigma(h)*B(low)  (separable prefix-parity weights)
// ---------------------------------------------------------------------------
__global__ __launch_bounds__(256) void pass2(const float2* __restrict__ amp,
                                             const float* __restrict__ params,
                                             const float* __restrict__ Wv,
                                             float* __restrict__ pws) {
    __shared__ float  lre[4224];
    __shared__ float  lim[4224];
    __shared__ Coef   coef[8];          // coef[w] = wire w
    __shared__ float2 Asig[256];        // (A(h), sigma(h))
    __shared__ float  Btab[16];
    __shared__ float  wred[4];
    const int t        = threadIdx.x;
    const int b        = blockIdx.x >> 8;
    const int chunk    = blockIdx.x & 255;
    const int low_base = chunk * 16;

    if (t < 8) {
        double s1, c1, s2, c2;
        sincos(0.5 * (double)params[t],      &s1, &c1);
        sincos(0.5 * (double)params[t + NW], &s2, &c2);
        coef[t].a = (float)(c1 * c2);
        coef[t].d = (float)(s1 * s2);
        coef[t].e = (float)(s2 * c1);
        coef[t].f = (float)(c2 * s1);
    }
    {   // A(h) = sum_{i<8} W_i * (-1)^{parity(h>>(7-i))},  sigma(h) = (-1)^{parity(h)}
        int h = t;
        float A = 0.f;
        #pragma unroll
        for (int i = 0; i < 8; ++i)
            A += Wv[i] * (1.f - 2.f * (float)(__popc(h >> (7 - i)) & 1));
        Asig[h] = make_float2(A, 1.f - 2.f * (float)(__popc(h) & 1));
    }
    if (t < 16) {   // B(low) = sum_{i=8..19} W_i * (-1)^{parity(low>>(19-i))}
        int low = low_base + t;
        float Bs = 0.f;
        #pragma unroll
        for (int i = 8; i < 20; ++i)
            Bs += Wv[i] * (1.f - 2.f * (float)(__popc(low >> (19 - i)) & 1));
        Btab[t] = Bs;
    }

    const int l = t & 15, hi = t >> 4;
    const float2* src = amp + ((size_t)b << 20);
    float re[16], im[16];
    #pragma unroll
    for (int r = 0; r < 16; ++r) {      // 128B-contiguous per 16 lanes
        float2 v = src[(size_t)(hi * 16 + r) * 4096 + (size_t)(low_base + l)];
        re[r] = v.x; im[r] = v.y;
    }
    __syncthreads();                    // tables ready

    // Round 1: own h bits 0..3 (h = hi*16 + r); y bit 12+j -> wire 7-j
    stage16<0>(re, im, coef[7]);
    stage16<1>(re, im, coef[6]);
    stage16<2>(re, im, coef[5]);
    stage16<3>(re, im, coef[4]);
    // exchange: local index i = h*16 + l
    #pragma unroll
    for (int r = 0; r < 16; ++r) { int i = hi * 256 + r * 16 + l; lre[SK(i)] = re[r]; lim[SK(i)] = im[r]; }
    __syncthreads();
    #pragma unroll
    for (int r = 0; r < 16; ++r) { int i = r * 256 + t; re[r] = lre[SK(i)]; im[r] = lim[SK(i)]; }
    // Round 2: own h bits 4..7 (h = r*16 + hi); y bit 16+j -> wire 3-j
    stage16<0>(re, im, coef[3]);
    stage16<1>(re, im, coef[2]);
    stage16<2>(re, im, coef[1]);
    stage16<3>(re, im, coef[0]);

    // fused weighted-probability accumulation
    const float Bl = Btab[l];
    float acc = 0.f;
    #pragma unroll
    for (int r = 0; r < 16; ++r) {
        int h = r * 16 + hi;
        float2 as = Asig[h];
        float g = fmaf(as.y, Bl, as.x);
        float p = fmaf(re[r], re[r], im[r] * im[r]);
        acc = fmaf(p, g, acc);
    }
    #pragma unroll
    for (int off = 32; off > 0; off >>= 1) acc += __shfl_down(acc, off, 64);
    if ((t & 63) == 0) wred[t >> 6] = acc;
    __syncthreads();
    if (t == 0) pws[blockIdx.x] = (wred[0] + wred[1]) + (wred[2] + wred[3]);
}

// ---------------------------------------------------------------------------
// Final: deterministic reduction of 256 partials per batch + bias
// ---------------------------------------------------------------------------
__global__ void finalk(const float* __restrict__ pws, const float* __restrict__ bias,
                       float* __restrict__ out) {
    const int t = threadIdx.x;
    const int b = t >> 3, j = t & 7;
    float s = 0.f;
    #pragma unroll 4
    for (int k = 0; k < 32; ++k) s += pws[b * 256 + j * 32 + k];
    s += __shfl_down(s, 4, 8);
    s += __shfl_down(s, 2, 8);
    s += __shfl_down(s, 1, 8);
    if (j == 0) out[b] = s + bias[0];
}

extern "C" void kernel_launch(void* const* d_in, const int* in_sizes, int n_in,
                              void* d_out, int out_size, void* d_ws, size_t ws_size,
                              hipStream_t stream) {
    const float* state  = (const float*)d_in[0];   // (32, 2^20) f32, row-normalized
    const float* params = (const float*)d_in[1];   // (40,) f32
    const float* Wv     = (const float*)d_in[2];   // (1,20) f32
    const float* bias   = (const float*)d_in[3];   // (1,)  f32
    float* out = (float*)d_out;                    // (32,) f32

    float2* amp = (float2*)d_ws;                                   // 256 MiB
    float*  pws = (float*)((char*)d_ws + (size_t)BATCH * DIM * sizeof(float2)); // 32 KiB

    pass1<<<BATCH * 256, 256, 0, stream>>>(state, params, amp);
    pass2<<<BATCH * 256, 256, 0, stream>>>(amp, params, Wv, pws);
    finalk<<<1, 256, 0, stream>>>(pws, bias, out);
}

// Round 2
// 151.627 us; speedup vs baseline: 1.1463x; 1.1463x over previous
//
#include <hip/hip_runtime.h>
#include <hip/hip_fp16.h>

#define NW    20
#define BATCH 32

struct Coef { float a, d, e, f; };

// n0 = (a+id)x0 + (-e-if)x1 ; n1 = (e-if)x0 + (a-id)x1
__device__ __forceinline__ void bfly(float& x0r, float& x0i, float& x1r, float& x1i,
                                     float a, float d, float e, float f) {
    float n0r = fmaf(a, x0r, fmaf(-d, x0i, fmaf(-e, x1r,  f * x1i)));
    float n0i = fmaf(a, x0i, fmaf( d, x0r, fmaf(-e, x1i, -f * x1r)));
    float n1r = fmaf(e, x0r, fmaf( f, x0i, fmaf( a, x1r,  d * x1i)));
    float n1i = fmaf(e, x0i, fmaf(-f, x0r, fmaf( a, x1i, -d * x1r)));
    x0r = n0r; x0i = n0i; x1r = n1r; x1i = n1i;
}

template<int JB>
__device__ __forceinline__ void stage16(float (&re)[16], float (&im)[16], const Coef u) {
    #pragma unroll
    for (int base = 0; base < 16; ++base)
        if (!(base & (1 << JB)))
            bfly(re[base], im[base], re[base | (1 << JB)], im[base | (1 << JB)],
                 u.a, u.d, u.e, u.f);
}

// first stage of pass1: imag inputs are exactly 0 -> half the ops
template<int JB>
__device__ __forceinline__ void stage16_first(float (&re)[16], float (&im)[16], const Coef u) {
    #pragma unroll
    for (int base = 0; base < 16; ++base)
        if (!(base & (1 << JB))) {
            int p = base | (1 << JB);
            float x0 = re[base], x1 = re[p];
            re[base] = fmaf(u.a, x0, -u.e * x1);
            im[base] = fmaf(u.d, x0, -u.f * x1);
            re[p]    = fmaf(u.e, x0,  u.a * x1);
            im[p]    = fmaf(-u.f, x0, -u.d * x1);
        }
}

// fused RY(t2)*RX(t1) coefficients, once for all blocks. coef[8] carries the
// x1024 fp16-range scale (applied exactly once across pass1's 12 stages).
__global__ void setupk(const float* __restrict__ params, Coef* __restrict__ coefs) {
    int w = threadIdx.x;
    if (w < NW) {
        double s1, c1, s2, c2;
        sincos(0.5 * (double)params[w],      &s1, &c1);   // RX
        sincos(0.5 * (double)params[w + NW], &s2, &c2);   // RY
        float sc = (w == 8) ? 1024.f : 1.f;
        coefs[w].a = (float)(c1 * c2) * sc;
        coefs[w].d = (float)(s1 * s2) * sc;
        coefs[w].e = (float)(s2 * c1) * sc;
        coefs[w].f = (float)(c2 * s1) * sc;
    }
}

// ---------------------------------------------------------------------------
// Pass 1: wires 8..19 (y bits 0..11). Block = one h (bits 12..19), 4096 amps.
// Round 1 owns bits {0,1,10,11} -> the global load is 4 coalesced float4s.
// All LDS addresses are base + compile-time immediate (skew SK(i)=i+(i>>5)
// folded algebraically; all patterns verified <=3-way bank aliasing).
// ---------------------------------------------------------------------------
__global__ __launch_bounds__(256) void pass1(const float* __restrict__ state,
                                             const Coef* __restrict__ coefs,
                                             __half2* __restrict__ amp) {
    __shared__ float lre[4224];
    __shared__ float lim[4224];
    const int t     = threadIdx.x;
    const int b     = blockIdx.x >> 8;
    const int chunk = blockIdx.x & 255;

    const float4* src = (const float4*)(state + ((size_t)b << 20) + ((size_t)chunk << 12));
    float re[16], im[16];
    #pragma unroll
    for (int k = 0; k < 4; ++k) {           // i = 4t + m + 1024k  (coalesced)
        float4 v = src[k * 256 + t];
        re[k*4+0] = v.x; re[k*4+1] = v.y; re[k*4+2] = v.z; re[k*4+3] = v.w;
    }
    // Round 1: r-bits {0,1,2,3} = i-bits {0,1,10,11} -> wires {19,18,9,8}
    stage16_first<0>(re, im, coefs[19]);
    stage16<1>(re, im, coefs[18]);
    stage16<2>(re, im, coefs[9]);
    stage16<3>(re, im, coefs[8]);           // carries the x1024 scale
    {   // write i = (r&3) + 4t + 1024(r>>2); SK -> p1 + (r&3) + 1056(r>>2)
        const int p1 = 4 * t + (t >> 3);
        #pragma unroll
        for (int r = 0; r < 16; ++r) {
            const int a = p1 + (r & 3) + 1056 * (r >> 2);
            lre[a] = re[r]; lim[a] = im[r];
        }
    }
    __syncthreads();

    // Round 2: own i-bits {2,3,4,5} -> wires {17,16,15,14}
    // i = (t&3) + 4(r&3) + 16(r>>2) + 64(t>>2); SK -> p2 + c + (c>>5)
    const int p2 = (t & 3) + 66 * (t >> 2);
    #pragma unroll
    for (int r = 0; r < 16; ++r) {
        const int c = 4 * (r & 3) + 16 * (r >> 2);
        const int a = p2 + c + (c >> 5);
        re[r] = lre[a]; im[r] = lim[a];
    }
    stage16<0>(re, im, coefs[17]);
    stage16<1>(re, im, coefs[16]);
    stage16<2>(re, im, coefs[15]);
    stage16<3>(re, im, coefs[14]);
    #pragma unroll
    for (int r = 0; r < 16; ++r) {
        const int c = 4 * (r & 3) + 16 * (r >> 2);
        const int a = p2 + c + (c >> 5);
        lre[a] = re[r]; lim[a] = im[r];
    }
    __syncthreads();

    // Round 3: own i-bits {6,7,8,9} -> wires {13,12,11,10}
    // i = (t&63) + 64(r&3) + 256(r>>2) + 1024(t>>6); SK -> p3 + 66(r&3) + 264(r>>2)
    const int p3 = (t & 63) + ((t & 63) >> 5) + 1056 * (t >> 6);
    #pragma unroll
    for (int r = 0; r < 16; ++r) {
        const int a = p3 + 66 * (r & 3) + 264 * (r >> 2);
        re[r] = lre[a]; im[r] = lim[a];
    }
    stage16<0>(re, im, coefs[13]);
    stage16<1>(re, im, coefs[12]);
    stage16<2>(re, im, coefs[11]);
    stage16<3>(re, im, coefs[10]);

    __half2* dst = amp + ((size_t)b << 20) + ((size_t)chunk << 12);
    const int sbase = (t & 63) + 1024 * (t >> 6);
    #pragma unroll
    for (int r = 0; r < 16; ++r)            // lanes consecutive: coalesced
        dst[sbase + 64 * (r & 3) + 256 * (r >> 2)] = __floats2half2_rn(re[r], im[r]);
}

// ---------------------------------------------------------------------------
// Pass 2: wires 0..7 (y bits 12..19) + fused |psi|^2 * g(y) reduction.
// g(y) = A(h) + sigma(h)*B(low); amps arrive fp16 (x1024 scaled).
// ---------------------------------------------------------------------------
__global__ __launch_bounds__(256) void pass2(const __half2* __restrict__ amp,
                                             const Coef* __restrict__ coefs,
                                             const float* __restrict__ Wv,
                                             float* __restrict__ pws) {
    __shared__ float  lre[4224];
    __shared__ float  lim[4224];
    __shared__ float2 Asig[256];
    __shared__ float  Btab[16];
    __shared__ float  wred[4];
    const int t        = threadIdx.x;
    const int b        = blockIdx.x >> 8;
    const int chunk    = blockIdx.x & 255;
    const int low_base = chunk * 16;
    const int l = t & 15, hi = t >> 4;

    {   // A(h) = sum_{i<8} W_i * (-1)^{parity(h>>(7-i))}, sigma(h) = (-1)^{parity(h)}
        float A = 0.f;
        #pragma unroll
        for (int i = 0; i < 8; ++i)
            A += Wv[i] * (1.f - 2.f * (float)(__popc(t >> (7 - i)) & 1));
        Asig[t] = make_float2(A, 1.f - 2.f * (float)(__popc(t) & 1));
    }
    if (t < 16) {   // B(low) = sum_{i=8..19} W_i * (-1)^{parity(low>>(19-i))}
        int low = low_base + t;
        float Bs = 0.f;
        #pragma unroll
        for (int i = 8; i < 20; ++i)
            Bs += Wv[i] * (1.f - 2.f * (float)(__popc(low >> (19 - i)) & 1));
        Btab[t] = Bs;
    }

    const __half2* src = amp + ((size_t)b << 20) + low_base + l;
    float re[16], im[16];
    #pragma unroll
    for (int r = 0; r < 16; ++r) {          // 64B-contiguous per 16 lanes; L2/L3-hot
        float2 v = __half22float2(src[(size_t)(hi * 16 + r) * 4096]);
        re[r] = v.x; im[r] = v.y;
    }
    // Round 1: h-bits 0..3 -> wires 7,6,5,4
    stage16<0>(re, im, coefs[7]);
    stage16<1>(re, im, coefs[6]);
    stage16<2>(re, im, coefs[5]);
    stage16<3>(re, im, coefs[4]);
    {   // write i = 264*hi + l + 16r + (r>>1)  (SK folded)
        const int p = 264 * hi + l;
        #pragma unroll
        for (int r = 0; r < 16; ++r) {
            const int a = p + 16 * r + (r >> 1);
            lre[a] = re[r]; lim[a] = im[r];
        }
    }
    __syncthreads();
    {   // read i = r*256 + t; SK -> (t + (t>>5)) + 264r
        const int p = t + (t >> 5);
        #pragma unroll
        for (int r = 0; r < 16; ++r) {
            const int a = p + 264 * r;
            re[r] = lre[a]; im[r] = lim[a];
        }
    }
    // Round 2: h-bits 4..7 -> wires 3,2,1,0
    stage16<0>(re, im, coefs[3]);
    stage16<1>(re, im, coefs[2]);
    stage16<2>(re, im, coefs[1]);
    stage16<3>(re, im, coefs[0]);

    // fused weighted-probability accumulation (h = r*16 + hi)
    const float Bl = Btab[l];
    float acc = 0.f;
    #pragma unroll
    for (int r = 0; r < 16; ++r) {
        float2 as = Asig[r * 16 + hi];
        float g = fmaf(as.y, Bl, as.x);
        float p = fmaf(re[r], re[r], im[r] * im[r]);
        acc = fmaf(p, g, acc);
    }
    #pragma unroll
    for (int off = 32; off > 0; off >>= 1) acc += __shfl_down(acc, off, 64);
    if ((t & 63) == 0) wred[t >> 6] = acc;
    __syncthreads();
    if (t == 0) pws[blockIdx.x] = (wred[0] + wred[1]) + (wred[2] + wred[3]);
}

// ---------------------------------------------------------------------------
// Final: deterministic reduction of 256 partials per batch, undo 2^20 scale
// ---------------------------------------------------------------------------
__global__ void finalk(const float* __restrict__ pws, const float* __restrict__ bias,
                       float* __restrict__ out) {
    const int t = threadIdx.x;
    const int b = t >> 3, j = t & 7;
    float s = 0.f;
    #pragma unroll 4
    for (int k = 0; k < 32; ++k) s += pws[b * 256 + j * 32 + k];
    s += __shfl_down(s, 4, 8);
    s += __shfl_down(s, 2, 8);
    s += __shfl_down(s, 1, 8);
    if (j == 0) out[b] = s * (1.f / 1048576.f) + bias[0];
}

extern "C" void kernel_launch(void* const* d_in, const int* in_sizes, int n_in,
                              void* d_out, int out_size, void* d_ws, size_t ws_size,
                              hipStream_t stream) {
    const float* state  = (const float*)d_in[0];   // (32, 2^20) f32
    const float* params = (const float*)d_in[1];   // (40,) f32
    const float* Wv     = (const float*)d_in[2];   // (1,20) f32
    const float* bias   = (const float*)d_in[3];   // (1,)  f32
    float* out = (float*)d_out;                    // (32,) f32

    __half2* amp  = (__half2*)d_ws;                                        // 128 MiB
    float*   pws  = (float*)((char*)d_ws + (size_t)BATCH * (1u << 20) * 4); // 32 KiB
    Coef*    coefs = (Coef*)((char*)d_ws + (size_t)BATCH * (1u << 20) * 4 + 8192 * 4);

    setupk<<<1, 64, 0, stream>>>(params, coefs);
    pass1 <<<BATCH * 256, 256, 0, stream>>>(state, coefs, amp);
    pass2 <<<BATCH * 256, 256, 0, stream>>>(amp, coefs, Wv, pws);
    finalk<<<1, 256, 0, stream>>>(pws, bias, out);
}

// Round 3
// 139.936 us; speedup vs baseline: 1.2421x; 1.0835x over previous
//
#include <hip/hip_runtime.h>
#include <hip/hip_fp16.h>

#define NW    20
#define BATCH 32

struct Coef { float a, d, e, f; };

// n0 = (a+id)x0 + (-e-if)x1 ; n1 = (e-if)x0 + (a-id)x1
__device__ __forceinline__ void bfly(float& x0r, float& x0i, float& x1r, float& x1i,
                                     float a, float d, float e, float f) {
    float n0r = fmaf(a, x0r, fmaf(-d, x0i, fmaf(-e, x1r,  f * x1i)));
    float n0i = fmaf(a, x0i, fmaf( d, x0r, fmaf(-e, x1i, -f * x1r)));
    float n1r = fmaf(e, x0r, fmaf( f, x0i, fmaf( a, x1r,  d * x1i)));
    float n1i = fmaf(e, x0i, fmaf(-f, x0r, fmaf( a, x1i, -d * x1r)));
    x0r = n0r; x0i = n0i; x1r = n1r; x1i = n1i;
}

template<int JB>
__device__ __forceinline__ void stage16(float (&re)[16], float (&im)[16], const Coef u) {
    #pragma unroll
    for (int base = 0; base < 16; ++base)
        if (!(base & (1 << JB)))
            bfly(re[base], im[base], re[base | (1 << JB)], im[base | (1 << JB)],
                 u.a, u.d, u.e, u.f);
}

// first stage of pass1: imag inputs are exactly 0 -> half the ops
template<int JB>
__device__ __forceinline__ void stage16_first(float (&re)[16], float (&im)[16], const Coef u) {
    #pragma unroll
    for (int base = 0; base < 16; ++base)
        if (!(base & (1 << JB))) {
            int p = base | (1 << JB);
            float x0 = re[base], x1 = re[p];
            re[base] = fmaf(u.a, x0, -u.e * x1);
            im[base] = fmaf(u.d, x0, -u.f * x1);
            re[p]    = fmaf(u.e, x0,  u.a * x1);
            im[p]    = fmaf(-u.f, x0, -u.d * x1);
        }
}

// fused RY(t2)*RX(t1) coefficients, once for all blocks. coef[8] carries the
// x1024 fp16-range scale (applied exactly once, before the first fp16 store).
__global__ void setupk(const float* __restrict__ params, Coef* __restrict__ coefs) {
    int w = threadIdx.x;
    if (w < NW) {
        double s1, c1, s2, c2;
        sincos(0.5 * (double)params[w],      &s1, &c1);   // RX
        sincos(0.5 * (double)params[w + NW], &s2, &c2);   // RY
        float sc = (w == 8) ? 1024.f : 1.f;
        coefs[w].a = (float)(c1 * c2) * sc;
        coefs[w].d = (float)(s1 * s2) * sc;
        coefs[w].e = (float)(s2 * c1) * sc;
        coefs[w].f = (float)(c2 * s1) * sc;
    }
}

// ---------------------------------------------------------------------------
// Pass 1: wires 8..19 (y bits 0..11). Block = one h-chunk (bits 12..19).
// half2-packed LDS exchange: 16.9 KiB LDS -> 8 blocks/CU (100% occupancy).
// All LDS addresses are base + compile-time immediate; skew SK(i)=i+(i>>5)
// folded algebraically (<=2-way bank aliasing everywhere).
// ---------------------------------------------------------------------------
__global__ __launch_bounds__(256, 8) void pass1(const float* __restrict__ state,
                                                const Coef* __restrict__ coefs,
                                                __half2* __restrict__ amp) {
    __shared__ __half2 lh[4224];
    const int t     = threadIdx.x;
    const int b     = blockIdx.x >> 8;
    const int chunk = blockIdx.x & 255;

    const float4* src = (const float4*)(state + ((size_t)b << 20) + ((size_t)chunk << 12));
    float re[16], im[16];
    #pragma unroll
    for (int k = 0; k < 4; ++k) {           // i = 4t + m + 1024k  (coalesced)
        float4 v = src[k * 256 + t];
        re[k*4+0] = v.x; re[k*4+1] = v.y; re[k*4+2] = v.z; re[k*4+3] = v.w;
    }
    // Round 1: r-bits {0,1,2,3} = i-bits {0,1,10,11} -> wires {19,18,9,8}
    stage16_first<0>(re, im, coefs[19]);
    stage16<1>(re, im, coefs[18]);
    stage16<2>(re, im, coefs[9]);
    stage16<3>(re, im, coefs[8]);           // carries the x1024 scale
    {   // write i = (r&3) + 4t + 1024(r>>2); SK -> p1 + (r&3) + 1056(r>>2)
        const int p1 = 4 * t + (t >> 3);
        #pragma unroll
        for (int r = 0; r < 16; ++r)
            lh[p1 + (r & 3) + 1056 * (r >> 2)] = __floats2half2_rn(re[r], im[r]);
    }
    __syncthreads();

    // Round 2: own i-bits {2,3,4,5} -> wires {17,16,15,14}
    // i = (t&3) + 4(r&3) + 16(r>>2) + 64(t>>2); SK -> p2 + c + (c>>5)
    const int p2 = (t & 3) + 66 * (t >> 2);
    #pragma unroll
    for (int r = 0; r < 16; ++r) {
        const int c = 4 * (r & 3) + 16 * (r >> 2);
        float2 v = __half22float2(lh[p2 + c + (c >> 5)]);
        re[r] = v.x; im[r] = v.y;
    }
    stage16<0>(re, im, coefs[17]);
    stage16<1>(re, im, coefs[16]);
    stage16<2>(re, im, coefs[15]);
    stage16<3>(re, im, coefs[14]);
    #pragma unroll
    for (int r = 0; r < 16; ++r) {          // write-set == own read-set: no barrier
        const int c = 4 * (r & 3) + 16 * (r >> 2);
        lh[p2 + c + (c >> 5)] = __floats2half2_rn(re[r], im[r]);
    }
    __syncthreads();

    // Round 3: own i-bits {6,7,8,9} -> wires {13,12,11,10}
    // i = (t&63) + 64(r&3) + 256(r>>2) + 1024(t>>6); SK -> p3 + 66(r&3) + 264(r>>2)
    const int p3 = (t & 63) + ((t & 63) >> 5) + 1056 * (t >> 6);
    #pragma unroll
    for (int r = 0; r < 16; ++r) {
        float2 v = __half22float2(lh[p3 + 66 * (r & 3) + 264 * (r >> 2)]);
        re[r] = v.x; im[r] = v.y;
    }
    stage16<0>(re, im, coefs[13]);
    stage16<1>(re, im, coefs[12]);
    stage16<2>(re, im, coefs[11]);
    stage16<3>(re, im, coefs[10]);

    __half2* dst = amp + ((size_t)b << 20) + ((size_t)chunk << 12);
    const int sbase = (t & 63) + 1024 * (t >> 6);
    #pragma unroll
    for (int r = 0; r < 16; ++r)            // lanes consecutive: coalesced
        dst[sbase + 64 * (r & 3) + 256 * (r >> 2)] = __floats2half2_rn(re[r], im[r]);
}

// ---------------------------------------------------------------------------
// Pass 2: wires 0..7 (y bits 12..19) + fused |psi|^2 * g(y) reduction.
// g(y) = A(h) + sigma(h)*B(low); amps arrive fp16 (x1024 scaled).
// half2-packed LDS exchange: ~19.5 KiB total LDS -> 8 blocks/CU.
// ---------------------------------------------------------------------------
__global__ __launch_bounds__(256, 8) void pass2(const __half2* __restrict__ amp,
                                                const Coef* __restrict__ coefs,
                                                const float* __restrict__ Wv,
                                                float* __restrict__ pws) {
    __shared__ __half2 lh[4224];
    __shared__ float2  Asig[256];
    __shared__ float   Btab[16];
    __shared__ float   wred[4];
    const int t        = threadIdx.x;
    const int b        = blockIdx.x >> 8;
    const int chunk    = blockIdx.x & 255;
    const int low_base = chunk * 16;
    const int l = t & 15, hi = t >> 4;

    {   // A(h) = sum_{i<8} W_i * (-1)^{parity(h>>(7-i))}, sigma(h) = (-1)^{parity(h)}
        float A = 0.f;
        #pragma unroll
        for (int i = 0; i < 8; ++i)
            A += Wv[i] * (1.f - 2.f * (float)(__popc(t >> (7 - i)) & 1));
        Asig[t] = make_float2(A, 1.f - 2.f * (float)(__popc(t) & 1));
    }
    if (t < 16) {   // B(low) = sum_{i=8..19} W_i * (-1)^{parity(low>>(19-i))}
        int low = low_base + t;
        float Bs = 0.f;
        #pragma unroll
        for (int i = 8; i < 20; ++i)
            Bs += Wv[i] * (1.f - 2.f * (float)(__popc(low >> (19 - i)) & 1));
        Btab[t] = Bs;
    }

    const __half2* src = amp + ((size_t)b << 20) + low_base + l;
    float re[16], im[16];
    #pragma unroll
    for (int r = 0; r < 16; ++r) {          // 64B-contiguous per 16 lanes; L3-hot
        float2 v = __half22float2(src[(size_t)(hi * 16 + r) * 4096]);
        re[r] = v.x; im[r] = v.y;
    }
    // Round 1: h-bits 0..3 -> wires 7,6,5,4
    stage16<0>(re, im, coefs[7]);
    stage16<1>(re, im, coefs[6]);
    stage16<2>(re, im, coefs[5]);
    stage16<3>(re, im, coefs[4]);
    {   // write i = 264*hi + l + 16r + (r>>1)  (SK folded)
        const int p = 264 * hi + l;
        #pragma unroll
        for (int r = 0; r < 16; ++r)
            lh[p + 16 * r + (r >> 1)] = __floats2half2_rn(re[r], im[r]);
    }
    __syncthreads();                        // also covers Asig/Btab visibility
    {   // read i = r*256 + t; SK -> (t + (t>>5)) + 264r
        const int p = t + (t >> 5);
        #pragma unroll
        for (int r = 0; r < 16; ++r) {
            float2 v = __half22float2(lh[p + 264 * r]);
            re[r] = v.x; im[r] = v.y;
        }
    }
    // Round 2: h-bits 4..7 -> wires 3,2,1,0
    stage16<0>(re, im, coefs[3]);
    stage16<1>(re, im, coefs[2]);
    stage16<2>(re, im, coefs[1]);
    stage16<3>(re, im, coefs[0]);

    // fused weighted-probability accumulation (h = r*16 + hi)
    const float Bl = Btab[l];
    float acc = 0.f;
    #pragma unroll
    for (int r = 0; r < 16; ++r) {
        float2 as = Asig[r * 16 + hi];
        float g = fmaf(as.y, Bl, as.x);
        float p = fmaf(re[r], re[r], im[r] * im[r]);
        acc = fmaf(p, g, acc);
    }
    #pragma unroll
    for (int off = 32; off > 0; off >>= 1) acc += __shfl_down(acc, off, 64);
    if ((t & 63) == 0) wred[t >> 6] = acc;
    __syncthreads();
    if (t == 0) pws[blockIdx.x] = (wred[0] + wred[1]) + (wred[2] + wred[3]);
}

// ---------------------------------------------------------------------------
// Final: deterministic reduction of 256 partials per batch, undo 2^20 scale
// ---------------------------------------------------------------------------
__global__ void finalk(const float* __restrict__ pws, const float* __restrict__ bias,
                       float* __restrict__ out) {
    const int t = threadIdx.x;
    const int b = t >> 3, j = t & 7;
    float s = 0.f;
    #pragma unroll 4
    for (int k = 0; k < 32; ++k) s += pws[b * 256 + j * 32 + k];
    s += __shfl_down(s, 4, 8);
    s += __shfl_down(s, 2, 8);
    s += __shfl_down(s, 1, 8);
    if (j == 0) out[b] = s * (1.f / 1048576.f) + bias[0];
}

extern "C" void kernel_launch(void* const* d_in, const int* in_sizes, int n_in,
                              void* d_out, int out_size, void* d_ws, size_t ws_size,
                              hipStream_t stream) {
    const float* state  = (const float*)d_in[0];   // (32, 2^20) f32
    const float* params = (const float*)d_in[1];   // (40,) f32
    const float* Wv     = (const float*)d_in[2];   // (1,20) f32
    const float* bias   = (const float*)d_in[3];   // (1,)  f32
    float* out = (float*)d_out;                    // (32,) f32

    __half2* amp  = (__half2*)d_ws;                                         // 128 MiB
    float*   pws  = (float*)((char*)d_ws + (size_t)BATCH * (1u << 20) * 4); // 32 KiB
    Coef*    coefs = (Coef*)((char*)d_ws + (size_t)BATCH * (1u << 20) * 4 + 8192 * 4);

    setupk<<<1, 64, 0, stream>>>(params, coefs);
    pass1 <<<BATCH * 256, 256, 0, stream>>>(state, coefs, amp);
    pass2 <<<BATCH * 256, 256, 0, stream>>>(amp, coefs, Wv, pws);
    finalk<<<1, 256, 0, stream>>>(pws, bias, out);
}

// Round 5
// 120.263 us; speedup vs baseline: 1.4453x; 1.1636x over previous
//
#include <hip/hip_runtime.h>
#include <hip/hip_fp16.h>

#define NW    20
#define BATCH 32

// packed-fp16 coefficient sextet for one wire's fused RY*RX unitary
// U = [[a+id, -e-if],[e-if, a-id]]
struct PkW { __half2 A, Dp, Dn, E, En, F; };

__device__ __forceinline__ __half2 h2swap(__half2 v) {
    __half2 r; r.x = v.y; r.y = v.x; return r;   // folds into VOP3P op_sel
}

__device__ __forceinline__ __half2 pkrtz(float lo, float hi) {
    typedef __fp16 f16x2 __attribute__((ext_vector_type(2)));
    f16x2 v = __builtin_amdgcn_cvt_pkrtz(lo, hi);
    return *reinterpret_cast<__half2*>(&v);
}

// packed complex butterfly: x0' = (a+id)x0 + (-e-if)x1 ; x1' = (e-if)x0 + (a-id)x1
// x = (re,im) in one half2; s = swapped halves; 8 pk ops total.
__device__ __forceinline__ void bflyh(__half2& x0, __half2& x1, const PkW& u) {
    __half2 s0 = h2swap(x0), s1 = h2swap(x1);
    __half2 n0 = __hfma2(u.A, x0, __hfma2(u.Dp, s0, __hfma2(u.En, x1, __hmul2(u.F,  s1))));
    __half2 n1 = __hfma2(u.E, x0, __hfma2(u.F,  s0, __hfma2(u.A,  x1, __hmul2(u.Dn, s1))));
    x0 = n0; x1 = n1;
}

template<int JB>
__device__ __forceinline__ void stage16h(__half2 (&x)[16], const PkW& u) {
    #pragma unroll
    for (int base = 0; base < 16; ++base)
        if (!(base & (1 << JB)))
            bflyh(x[base], x[base | (1 << JB)], u);
}

// cbuf layout: [0..3] = wire19 f32 (a,d,e,f)*1024 ; then PkW[20] at cbuf+4
__global__ void setupk(const float* __restrict__ params, float* __restrict__ cbuf) {
    int w = threadIdx.x;
    if (w < NW) {
        double s1, c1, s2, c2;
        sincos(0.5 * (double)params[w],      &s1, &c1);   // RX
        sincos(0.5 * (double)params[w + NW], &s2, &c2);   // RY
        float a = (float)(c1 * c2), d = (float)(s1 * s2);
        float e = (float)(s2 * c1), f = (float)(c2 * s1);
        if (w == 19) {   // first pass1 stage stays f32 and carries the x1024 scale
            cbuf[0] = a * 1024.f; cbuf[1] = d * 1024.f;
            cbuf[2] = e * 1024.f; cbuf[3] = f * 1024.f;
        }
        PkW pw;
        pw.A  = __floats2half2_rn( a,  a);
        pw.Dp = __floats2half2_rn(-d,  d);
        pw.Dn = __floats2half2_rn( d, -d);
        pw.E  = __floats2half2_rn( e,  e);
        pw.En = __floats2half2_rn(-e, -e);
        pw.F  = __floats2half2_rn( f, -f);
        ((PkW*)(cbuf + 4))[w] = pw;
    }
}

// ---------------------------------------------------------------------------
// Pass 1: wires 8..19 (y bits 0..11). Block = one 4096-amp chunk.
// Stage 1 f32 (real input, x1024 scale) -> 11 packed-fp16 stages.
// LDS stays half2-packed; skew SK(i)=i+(i>>5) folded to immediates.
// ---------------------------------------------------------------------------
__global__ __launch_bounds__(256, 8) void pass1(const float* __restrict__ state,
                                                const float* __restrict__ cbuf,
                                                __half2* __restrict__ amp) {
    __shared__ __half2 lh[4224];
    const int t     = threadIdx.x;
    const int b     = blockIdx.x >> 8;
    const int chunk = blockIdx.x & 255;
    const PkW* PW = (const PkW*)(cbuf + 4);
    const float a19 = cbuf[0], d19 = cbuf[1], e19 = cbuf[2], f19 = cbuf[3];

    const float4* src = (const float4*)(state + ((size_t)b << 20) + ((size_t)chunk << 12));
    float u[16];
    #pragma unroll
    for (int k = 0; k < 4; ++k) {           // i = 4t + m + 1024k (coalesced)
        float4 v = src[k * 256 + t];
        u[k*4+0] = v.x; u[k*4+1] = v.y; u[k*4+2] = v.z; u[k*4+3] = v.w;
    }
    // Round 1: r-bits {0,1,2,3} = i-bits {0,1,10,11} -> wires {19,18,9,8}
    __half2 x[16];
    #pragma unroll
    for (int r = 0; r < 16; r += 2) {       // wire 19 on real input, f32 + pack
        float u0 = u[r], u1 = u[r + 1];
        x[r]     = pkrtz(fmaf(a19, u0, -e19 * u1), fmaf( d19, u0, -f19 * u1));
        x[r + 1] = pkrtz(fmaf(e19, u0,  a19 * u1), fmaf(-f19, u0, -d19 * u1));
    }
    {
        const PkW uw18 = PW[18], uw9 = PW[9], uw8 = PW[8];
        stage16h<1>(x, uw18);
        stage16h<2>(x, uw9);
        stage16h<3>(x, uw8);
    }
    {   // write i = (r&3) + 4t + 1024(r>>2); SK -> p1 + (r&3) + 1056(r>>2)
        const int p1 = 4 * t + (t >> 3);
        #pragma unroll
        for (int r = 0; r < 16; ++r)
            lh[p1 + (r & 3) + 1056 * (r >> 2)] = x[r];
    }
    __syncthreads();

    // Round 2: own i-bits {2,3,4,5} -> wires {17,16,15,14}
    const int p2 = (t & 3) + 66 * (t >> 2);
    #pragma unroll
    for (int r = 0; r < 16; ++r) {
        const int c = 4 * (r & 3) + 16 * (r >> 2);
        x[r] = lh[p2 + c + (c >> 5)];
    }
    {
        const PkW uw17 = PW[17], uw16 = PW[16], uw15 = PW[15], uw14 = PW[14];
        stage16h<0>(x, uw17);
        stage16h<1>(x, uw16);
        stage16h<2>(x, uw15);
        stage16h<3>(x, uw14);
    }
    #pragma unroll
    for (int r = 0; r < 16; ++r) {          // write-set == own read-set: no barrier
        const int c = 4 * (r & 3) + 16 * (r >> 2);
        lh[p2 + c + (c >> 5)] = x[r];
    }
    __syncthreads();

    // Round 3: own i-bits {6,7,8,9} -> wires {13,12,11,10}
    const int p3 = (t & 63) + ((t & 63) >> 5) + 1056 * (t >> 6);
    #pragma unroll
    for (int r = 0; r < 16; ++r)
        x[r] = lh[p3 + 66 * (r & 3) + 264 * (r >> 2)];
    {
        const PkW uw13 = PW[13], uw12 = PW[12], uw11 = PW[11], uw10 = PW[10];
        stage16h<0>(x, uw13);
        stage16h<1>(x, uw12);
        stage16h<2>(x, uw11);
        stage16h<3>(x, uw10);
    }

    __half2* dst = amp + ((size_t)b << 20) + ((size_t)chunk << 12);
    const int sbase = (t & 63) + 1024 * (t >> 6);
    #pragma unroll
    for (int r = 0; r < 16; ++r)            // lanes consecutive: coalesced
        dst[sbase + 64 * (r & 3) + 256 * (r >> 2)] = x[r];
}

// ---------------------------------------------------------------------------
// Pass 2: wires 0..7 (y bits 12..19), all packed-fp16, + fused |psi|^2 * g(y).
// g(y) = A(h) + sigma(h)*B(low)
// ---------------------------------------------------------------------------
__global__ __launch_bounds__(256, 8) void pass2(const __half2* __restrict__ amp,
                                                const float* __restrict__ cbuf,
                                                const float* __restrict__ Wv,
                                                float* __restrict__ pws) {
    __shared__ __half2 lh[4224];
    __shared__ float2  Asig[256];
    __shared__ float   Btab[16];
    __shared__ float   wred[4];
    const int t        = threadIdx.x;
    const int b        = blockIdx.x >> 8;
    const int chunk    = blockIdx.x & 255;
    const int low_base = chunk * 16;
    const int l = t & 15, hi = t >> 4;
    const PkW* PW = (const PkW*)(cbuf + 4);

    {   // A(h) = sum_{i<8} W_i * (-1)^{parity(h>>(7-i))}, sigma(h) = (-1)^{parity(h)}
        float A = 0.f;
        #pragma unroll
        for (int i = 0; i < 8; ++i)
            A += Wv[i] * (1.f - 2.f * (float)(__popc(t >> (7 - i)) & 1));
        Asig[t] = make_float2(A, 1.f - 2.f * (float)(__popc(t) & 1));
    }
    if (t < 16) {   // B(low) = sum_{i=8..19} W_i * (-1)^{parity(low>>(19-i))}
        int low = low_base + t;
        float Bs = 0.f;
        #pragma unroll
        for (int i = 8; i < 20; ++i)
            Bs += Wv[i] * (1.f - 2.f * (float)(__popc(low >> (19 - i)) & 1));
        Btab[t] = Bs;
    }

    const __half2* src = amp + ((size_t)b << 20) + low_base + l;
    __half2 x[16];
    #pragma unroll
    for (int r = 0; r < 16; ++r)            // 64B-contiguous per 16 lanes; L3-hot
        x[r] = src[(size_t)(hi * 16 + r) * 4096];
    // Round 1: h-bits 0..3 -> wires 7,6,5,4
    {
        const PkW uw7 = PW[7], uw6 = PW[6], uw5 = PW[5], uw4 = PW[4];
        stage16h<0>(x, uw7);
        stage16h<1>(x, uw6);
        stage16h<2>(x, uw5);
        stage16h<3>(x, uw4);
    }
    {   // write i = 264*hi + l + 16r + (r>>1)  (SK folded)
        const int p = 264 * hi + l;
        #pragma unroll
        for (int r = 0; r < 16; ++r)
            lh[p + 16 * r + (r >> 1)] = x[r];
    }
    __syncthreads();                        // also covers Asig/Btab visibility
    {   // read i = r*256 + t; SK -> (t + (t>>5)) + 264r
        const int p = t + (t >> 5);
        #pragma unroll
        for (int r = 0; r < 16; ++r)
            x[r] = lh[p + 264 * r];
    }
    // Round 2: h-bits 4..7 -> wires 3,2,1,0
    {
        const PkW uw3 = PW[3], uw2 = PW[2], uw1 = PW[1], uw0 = PW[0];
        stage16h<0>(x, uw3);
        stage16h<1>(x, uw2);
        stage16h<2>(x, uw1);
        stage16h<3>(x, uw0);
    }

    // fused weighted-probability accumulation (h = r*16 + hi), f32 epilogue
    const float Bl = Btab[l];
    float acc = 0.f;
    #pragma unroll
    for (int r = 0; r < 16; ++r) {
        float2 v  = __half22float2(x[r]);
        float2 as = Asig[r * 16 + hi];
        acc = fmaf(fmaf(v.x, v.x, v.y * v.y), fmaf(as.y, Bl, as.x), acc);
    }
    #pragma unroll
    for (int off = 32; off > 0; off >>= 1) acc += __shfl_down(acc, off, 64);
    if ((t & 63) == 0) wred[t >> 6] = acc;
    __syncthreads();
    if (t == 0) pws[blockIdx.x] = (wred[0] + wred[1]) + (wred[2] + wred[3]);
}

// ---------------------------------------------------------------------------
// Final: deterministic reduction of 256 partials per batch, undo 2^20 scale
// ---------------------------------------------------------------------------
__global__ void finalk(const float* __restrict__ pws, const float* __restrict__ bias,
                       float* __restrict__ out) {
    const int t = threadIdx.x;
    const int b = t >> 3, j = t & 7;
    float s = 0.f;
    #pragma unroll 4
    for (int k = 0; k < 32; ++k) s += pws[b * 256 + j * 32 + k];
    s += __shfl_down(s, 4, 8);
    s += __shfl_down(s, 2, 8);
    s += __shfl_down(s, 1, 8);
    if (j == 0) out[b] = s * (1.f / 1048576.f) + bias[0];
}

extern "C" void kernel_launch(void* const* d_in, const int* in_sizes, int n_in,
                              void* d_out, int out_size, void* d_ws, size_t ws_size,
                              hipStream_t stream) {
    const float* state  = (const float*)d_in[0];   // (32, 2^20) f32
    const float* params = (const float*)d_in[1];   // (40,) f32
    const float* Wv     = (const float*)d_in[2];   // (1,20) f32
    const float* bias   = (const float*)d_in[3];   // (1,)  f32
    float* out = (float*)d_out;                    // (32,) f32

    __half2* amp  = (__half2*)d_ws;                                          // 128 MiB
    float*   pws  = (float*)((char*)d_ws + (size_t)BATCH * (1u << 20) * 4);  // 32 KiB
    float*   cbuf = (float*)((char*)d_ws + (size_t)BATCH * (1u << 20) * 4 + 8192 * 4);

    setupk<<<1, 64, 0, stream>>>(params, cbuf);
    pass1 <<<BATCH * 256, 256, 0, stream>>>(state, cbuf, amp);
    pass2 <<<BATCH * 256, 256, 0, stream>>>(amp, cbuf, Wv, pws);
    finalk<<<1, 256, 0, stream>>>(pws, bias, out);
}

// Round 6
// 107.218 us; speedup vs baseline: 1.6212x; 1.1217x over previous
//
#include <hip/hip_runtime.h>
#include <hip/hip_fp16.h>

#define NW    20
#define BATCH 32

// splat coefficient set (7 packed splats) for one wire's fused RY*RX unitary
// U = [[a+id, -e-if],[e-if, a-id]]
struct PkW7 { __half2 a, d, dn, e, en, f, fn, pad; };   // 32 B

__device__ __forceinline__ __half2 pkrtz(float lo, float hi) {
    typedef __fp16 f16x2 __attribute__((ext_vector_type(2)));
    f16x2 v = __builtin_amdgcn_cvt_pkrtz(lo, hi);
    return *reinterpret_cast<__half2*>(&v);
}
__device__ __forceinline__ unsigned h2u(__half2 v) { return *reinterpret_cast<unsigned*>(&v); }
__device__ __forceinline__ __half2 u2h(unsigned v) { return *reinterpret_cast<__half2*>(&v); }

// SoA packed butterfly: re/im in separate half2, each half2 = 2 batch states.
// Pure element-wise pk ops - no swaps, no op_sel tricks.
template<int JB>
__device__ __forceinline__ void stage16s(__half2 (&xr)[16], __half2 (&xi)[16], const PkW7 u) {
    #pragma unroll
    for (int base = 0; base < 16; ++base)
        if (!(base & (1 << JB))) {
            const int p = base | (1 << JB);
            __half2 x0r = xr[base], x0i = xi[base], x1r = xr[p], x1i = xi[p];
            xr[base] = __hfma2(u.a, x0r, __hfma2(u.dn, x0i, __hfma2(u.en, x1r, __hmul2(u.f , x1i))));
            xi[base] = __hfma2(u.a, x0i, __hfma2(u.d , x0r, __hfma2(u.en, x1i, __hmul2(u.fn, x1r))));
            xr[p]    = __hfma2(u.e, x0r, __hfma2(u.f , x0i, __hfma2(u.a , x1r, __hmul2(u.d , x1i))));
            xi[p]    = __hfma2(u.e, x0i, __hfma2(u.fn, x0r, __hfma2(u.a , x1i, __hmul2(u.dn, x1r))));
        }
}

// cbuf layout: [0..3] = wire19 f32 (a,d,e,f)*1024 ; then PkW7[20] at cbuf+4
__global__ void setupk(const float* __restrict__ params, float* __restrict__ cbuf) {
    int w = threadIdx.x;
    if (w < NW) {
        double s1, c1, s2, c2;
        sincos(0.5 * (double)params[w],      &s1, &c1);   // RX
        sincos(0.5 * (double)params[w + NW], &s2, &c2);   // RY
        float a = (float)(c1 * c2), d = (float)(s1 * s2);
        float e = (float)(s2 * c1), f = (float)(c2 * s1);
        if (w == 19) {   // first pass1 stage stays f32 and carries the x1024 scale
            cbuf[0] = a * 1024.f; cbuf[1] = d * 1024.f;
            cbuf[2] = e * 1024.f; cbuf[3] = f * 1024.f;
        }
        PkW7 pw;
        pw.a  = __floats2half2_rn( a,  a);
        pw.d  = __floats2half2_rn( d,  d);
        pw.dn = __floats2half2_rn(-d, -d);
        pw.e  = __floats2half2_rn( e,  e);
        pw.en = __floats2half2_rn(-e, -e);
        pw.f  = __floats2half2_rn( f,  f);
        pw.fn = __floats2half2_rn(-f, -f);
        pw.pad = __floats2half2_rn(0.f, 0.f);
        ((PkW7*)(cbuf + 4))[w] = pw;
    }
}

// ---------------------------------------------------------------------------
// Pass 1: wires 8..19 (y bits 0..11). Block = one 4096-amp chunk x 2 batches
// (pr, pr+16) packed in half2 lanes. Stage 1 f32 (real input, x1024 scale),
// then 11 pure-pk stages. Skew SK(i)=i+(i>>5) folded to immediates.
// ---------------------------------------------------------------------------
__global__ __launch_bounds__(256, 4) void pass1(const float* __restrict__ state,
                                                const float* __restrict__ cbuf,
                                                uint2* __restrict__ amp) {
    __shared__ __half2 Lr[4224];
    __shared__ __half2 Li[4224];
    const int t     = threadIdx.x;
    const int pr    = blockIdx.x >> 8;      // batch pair: (pr, pr+16)
    const int chunk = blockIdx.x & 255;
    const PkW7* PW = (const PkW7*)(cbuf + 4);
    const float a19 = cbuf[0], d19 = cbuf[1], e19 = cbuf[2], f19 = cbuf[3];

    const float4* s0 = (const float4*)(state + ((size_t)pr << 20) + ((size_t)chunk << 12));
    const float4* s1 = (const float4*)((const float*)s0 + ((size_t)16 << 20));

    __half2 xr[16], xi[16];
    // Round 1: r-bits {0,1,2,3} = i-bits {0,1,10,11} -> wires {19,18,9,8}
    // wire 19 (i-bit 0) applied in f32 on the real input, then packed.
    #pragma unroll
    for (int k = 0; k < 4; ++k) {           // i = 4t + m + 1024k (coalesced)
        float4 v0 = s0[k * 256 + t];
        float4 v1 = s1[k * 256 + t];
        // pair (x,y)
        float r0a = fmaf(a19, v0.x, -e19 * v0.y), i0a = fmaf( d19, v0.x, -f19 * v0.y);
        float r1a = fmaf(e19, v0.x,  a19 * v0.y), i1a = fmaf(-f19, v0.x, -d19 * v0.y);
        float r0b = fmaf(a19, v1.x, -e19 * v1.y), i0b = fmaf( d19, v1.x, -f19 * v1.y);
        float r1b = fmaf(e19, v1.x,  a19 * v1.y), i1b = fmaf(-f19, v1.x, -d19 * v1.y);
        xr[4*k+0] = pkrtz(r0a, r0b); xi[4*k+0] = pkrtz(i0a, i0b);
        xr[4*k+1] = pkrtz(r1a, r1b); xi[4*k+1] = pkrtz(i1a, i1b);
        // pair (z,w)
        r0a = fmaf(a19, v0.z, -e19 * v0.w); i0a = fmaf( d19, v0.z, -f19 * v0.w);
        r1a = fmaf(e19, v0.z,  a19 * v0.w); i1a = fmaf(-f19, v0.z, -d19 * v0.w);
        r0b = fmaf(a19, v1.z, -e19 * v1.w); i0b = fmaf( d19, v1.z, -f19 * v1.w);
        r1b = fmaf(e19, v1.z,  a19 * v1.w); i1b = fmaf(-f19, v1.z, -d19 * v1.w);
        xr[4*k+2] = pkrtz(r0a, r0b); xi[4*k+2] = pkrtz(i0a, i0b);
        xr[4*k+3] = pkrtz(r1a, r1b); xi[4*k+3] = pkrtz(i1a, i1b);
    }
    stage16s<1>(xr, xi, PW[18]);
    stage16s<2>(xr, xi, PW[9]);
    stage16s<3>(xr, xi, PW[8]);
    {   // write i = (r&3) + 4t + 1024(r>>2); SK -> p1 + (r&3) + 1056(r>>2)
        const int p1 = 4 * t + (t >> 3);
        #pragma unroll
        for (int r = 0; r < 16; ++r) {
            const int a = p1 + (r & 3) + 1056 * (r >> 2);
            Lr[a] = xr[r]; Li[a] = xi[r];
        }
    }
    __syncthreads();

    // Round 2: own i-bits {2,3,4,5} -> wires {17,16,15,14}
    const int p2 = (t & 3) + 66 * (t >> 2);
    #pragma unroll
    for (int r = 0; r < 16; ++r) {
        const int c = 4 * (r & 3) + 16 * (r >> 2);
        const int a = p2 + c + (c >> 5);
        xr[r] = Lr[a]; xi[r] = Li[a];
    }
    stage16s<0>(xr, xi, PW[17]);
    stage16s<1>(xr, xi, PW[16]);
    stage16s<2>(xr, xi, PW[15]);
    stage16s<3>(xr, xi, PW[14]);
    #pragma unroll
    for (int r = 0; r < 16; ++r) {          // write-set == own read-set: no barrier
        const int c = 4 * (r & 3) + 16 * (r >> 2);
        const int a = p2 + c + (c >> 5);
        Lr[a] = xr[r]; Li[a] = xi[r];
    }
    __syncthreads();

    // Round 3: own i-bits {6,7,8,9} -> wires {13,12,11,10}
    const int p3 = (t & 63) + ((t & 63) >> 5) + 1056 * (t >> 6);
    #pragma unroll
    for (int r = 0; r < 16; ++r) {
        const int a = p3 + 66 * (r & 3) + 264 * (r >> 2);
        xr[r] = Lr[a]; xi[r] = Li[a];
    }
    stage16s<0>(xr, xi, PW[13]);
    stage16s<1>(xr, xi, PW[12]);
    stage16s<2>(xr, xi, PW[11]);
    stage16s<3>(xr, xi, PW[10]);

    uint2* dst = amp + ((size_t)pr << 20) + ((size_t)chunk << 12);
    const int sbase = (t & 63) + 1024 * (t >> 6);
    #pragma unroll
    for (int r = 0; r < 16; ++r) {          // lanes consecutive: 512B/wave-instr
        uint2 w; w.x = h2u(xr[r]); w.y = h2u(xi[r]);
        dst[sbase + 64 * (r & 3) + 256 * (r >> 2)] = w;
    }
}

// ---------------------------------------------------------------------------
// Pass 2: wires 0..7 (y bits 12..19), SoA pk stages, + fused |psi|^2 * g(y).
// g(y) = A(h) + sigma(h)*B(low); two batches per block (packed lanes).
// ---------------------------------------------------------------------------
__global__ __launch_bounds__(256, 4) void pass2(const uint2* __restrict__ amp,
                                                const float* __restrict__ cbuf,
                                                const float* __restrict__ Wv,
                                                float* __restrict__ pws) {
    __shared__ __half2 Lr[4224];
    __shared__ __half2 Li[4224];
    __shared__ float2  Asig[256];
    __shared__ float   Btab[16];
    __shared__ float   wred[8];
    const int t        = threadIdx.x;
    const int pr       = blockIdx.x >> 8;
    const int chunk    = blockIdx.x & 255;
    const int low_base = chunk * 16;
    const int l = t & 15, hi = t >> 4;
    const PkW7* PW = (const PkW7*)(cbuf + 4);

    {   // A(h) = sum_{i<8} W_i * (-1)^{parity(h>>(7-i))}, sigma(h) = (-1)^{parity(h)}
        float A = 0.f;
        #pragma unroll
        for (int i = 0; i < 8; ++i)
            A += Wv[i] * (1.f - 2.f * (float)(__popc(t >> (7 - i)) & 1));
        Asig[t] = make_float2(A, 1.f - 2.f * (float)(__popc(t) & 1));
    }
    if (t < 16) {   // B(low) = sum_{i=8..19} W_i * (-1)^{parity(low>>(19-i))}
        int low = low_base + t;
        float Bs = 0.f;
        #pragma unroll
        for (int i = 8; i < 20; ++i)
            Bs += Wv[i] * (1.f - 2.f * (float)(__popc(low >> (19 - i)) & 1));
        Btab[t] = Bs;
    }

    const uint2* src = amp + ((size_t)pr << 20) + low_base + l;
    __half2 xr[16], xi[16];
    #pragma unroll
    for (int r = 0; r < 16; ++r) {          // 128B-contiguous per 16 lanes; L3-hot
        uint2 w = src[(size_t)(hi * 16 + r) * 4096];
        xr[r] = u2h(w.x); xi[r] = u2h(w.y);
    }
    // Round 1: h-bits 0..3 -> wires 7,6,5,4
    stage16s<0>(xr, xi, PW[7]);
    stage16s<1>(xr, xi, PW[6]);
    stage16s<2>(xr, xi, PW[5]);
    stage16s<3>(xr, xi, PW[4]);
    {   // write i = 264*hi + l + 16r + (r>>1)  (SK folded)
        const int p = 264 * hi + l;
        #pragma unroll
        for (int r = 0; r < 16; ++r) {
            const int a = p + 16 * r + (r >> 1);
            Lr[a] = xr[r]; Li[a] = xi[r];
        }
    }
    __syncthreads();                        // also covers Asig/Btab visibility
    {   // read i = r*256 + t; SK -> (t + (t>>5)) + 264r
        const int p = t + (t >> 5);
        #pragma unroll
        for (int r = 0; r < 16; ++r) {
            const int a = p + 264 * r;
            xr[r] = Lr[a]; xi[r] = Li[a];
        }
    }
    // Round 2: h-bits 4..7 -> wires 3,2,1,0
    stage16s<0>(xr, xi, PW[3]);
    stage16s<1>(xr, xi, PW[2]);
    stage16s<2>(xr, xi, PW[1]);
    stage16s<3>(xr, xi, PW[0]);

    // fused weighted-probability accumulation (h = r*16 + hi), f32 epilogue
    const float Bl = Btab[l];
    float acc0 = 0.f, acc1 = 0.f;
    #pragma unroll
    for (int r = 0; r < 16; ++r) {
        float2 vr = __half22float2(xr[r]);
        float2 vi = __half22float2(xi[r]);
        float2 as = Asig[r * 16 + hi];
        float g = fmaf(as.y, Bl, as.x);
        acc0 = fmaf(fmaf(vr.x, vr.x, vi.x * vi.x), g, acc0);
        acc1 = fmaf(fmaf(vr.y, vr.y, vi.y * vi.y), g, acc1);
    }
    #pragma unroll
    for (int off = 32; off > 0; off >>= 1) {
        acc0 += __shfl_down(acc0, off, 64);
        acc1 += __shfl_down(acc1, off, 64);
    }
    if ((t & 63) == 0) { wred[(t >> 6) * 2] = acc0; wred[(t >> 6) * 2 + 1] = acc1; }
    __syncthreads();
    if (t < 2)
        pws[blockIdx.x * 2 + t] = (wred[t] + wred[2 + t]) + (wred[4 + t] + wred[6 + t]);
}

// ---------------------------------------------------------------------------
// Final: deterministic reduction of 256 partials per batch, undo 2^20 scale.
// Batch b lives in pair pr=b&15, slot s=b>>4.
// ---------------------------------------------------------------------------
__global__ void finalk(const float* __restrict__ pws, const float* __restrict__ bias,
                       float* __restrict__ out) {
    const int t = threadIdx.x;
    const int b = t >> 3, j = t & 7;
    const int pr = b & 15, sl = b >> 4;
    float s = 0.f;
    #pragma unroll 4
    for (int k = 0; k < 32; ++k) {
        const int c = j * 32 + k;
        s += pws[(pr * 256 + c) * 2 + sl];
    }
    s += __shfl_down(s, 4, 8);
    s += __shfl_down(s, 2, 8);
    s += __shfl_down(s, 1, 8);
    if (j == 0) out[b] = s * (1.f / 1048576.f) + bias[0];
}

extern "C" void kernel_launch(void* const* d_in, const int* in_sizes, int n_in,
                              void* d_out, int out_size, void* d_ws, size_t ws_size,
                              hipStream_t stream) {
    const float* state  = (const float*)d_in[0];   // (32, 2^20) f32
    const float* params = (const float*)d_in[1];   // (40,) f32
    const float* Wv     = (const float*)d_in[2];   // (1,20) f32
    const float* bias   = (const float*)d_in[3];   // (1,)  f32
    float* out = (float*)d_out;                    // (32,) f32

    uint2* amp  = (uint2*)d_ws;                                              // 128 MiB
    float* pws  = (float*)((char*)d_ws + (size_t)16 * (1u << 20) * 8);       // 32 KiB
    float* cbuf = (float*)((char*)d_ws + (size_t)16 * (1u << 20) * 8 + 8192 * 4);

    setupk<<<1, 64, 0, stream>>>(params, cbuf);
    pass1 <<<16 * 256, 256, 0, stream>>>(state, cbuf, amp);
    pass2 <<<16 * 256, 256, 0, stream>>>(amp, cbuf, Wv, pws);
    finalk<<<1, 256, 0, stream>>>(pws, bias, out);
}